// Round 16
// baseline (398.985 us; speedup 1.0000x reference)
//
#include <hip/hip_runtime.h>

// Problem constants (from reference)
#define Bx 4
#define Nn 10000
#define Ee 160000
#define Qq 256
#define Dd 128
#define Mm 64
#define Uu 126
#define Hh 128
#define Pp 7

// N padded to groups of 8 (1250 groups) + 2 pad groups for ragged K-tail
#define KG 1252

typedef unsigned short u16;
typedef __bf16 bf16x8 __attribute__((ext_vector_type(8)));
typedef float f32x4 __attribute__((ext_vector_type(4)));

__device__ __forceinline__ float b2f(u16 h){
  unsigned u = ((unsigned)h) << 16; float f; __builtin_memcpy(&f, &u, 4); return f;
}
// hardware RNE f32->bf16
__device__ __forceinline__ u16 f2b(float f){
  __bf16 h = (__bf16)f; u16 r; __builtin_memcpy(&r, &h, 2); return r;
}
__device__ __forceinline__ float ldin(const void* p, long i, int flag){
  return flag ? b2f(((const u16*)p)[i]) : ((const float*)p)[i];
}

// ---------------- dtype probe ----------------
__global__ void probe_kernel(const void* in0, int* flag){
  if (threadIdx.x == 0 && blockIdx.x == 0){
    const u16* p = (const u16*)in0;
    int cnt = 0;
    for (int i = 0; i < 256; i++){
      float a = fabsf(b2f(p[i]));
      if (a > 0.0009765625f && a < 32.0f) cnt++;
    }
    *flag = (cnt >= 240) ? 1 : 0;
  }
}

// ---------------- weight prep: convert + swizzle to MFMA B-frag layout ----------------
__global__ void prep_kernel(const void* w1e, const void* b1e, const void* w2e, const void* b2e,
                            const void* w1n, const void* b1n, const void* w2n, const void* b2n,
                            const int* __restrict__ flag,
                            u16* w1e_s, u16* w2e_s, u16* w1n_s, u16* w2n_s,
                            float* b1e_f, float* b2e_f, float* b1n_f, float* b2n_f)
{
  int f = *flag;
  for (int idx = blockIdx.x * blockDim.x + threadIdx.x; idx < 82368; idx += gridDim.x * blockDim.x){
    if (idx < 32768){                                   // w1e (256,128)
      int k = idx >> 7, h = idx & 127;
      w1e_s[(k >> 3) * 1024 + h * 8 + (k & 7)] = f2b(ldin(w1e, idx, f));
    } else if (idx < 40960){                            // w2e (128,64)
      int i2 = idx - 32768; int k = i2 >> 6, m2 = i2 & 63;
      w2e_s[(k >> 3) * 512 + m2 * 8 + (k & 7)] = f2b(ldin(w2e, i2, f));
    } else if (idx < 65536){                            // w1n (192,128)
      int i2 = idx - 40960; int k = i2 >> 7, h = i2 & 127;
      w1n_s[(k >> 3) * 1024 + h * 8 + (k & 7)] = f2b(ldin(w1n, i2, f));
    } else if (idx < 81920){                            // w2n (128,126) padded to 128 cols
      int i2 = idx - 65536; int k = i2 >> 7, u = i2 & 127;
      float v = (u < 126) ? ldin(w2n, (long)k * 126 + u, f) : 0.f;
      w2n_s[(k >> 3) * 1024 + u * 8 + (k & 7)] = f2b(v);
    } else if (idx < 82048){ b1e_f[idx - 81920] = ldin(b1e, idx - 81920, f); }
    else if (idx < 82112){ b2e_f[idx - 82048] = ldin(b2e, idx - 82048, f); }
    else if (idx < 82240){ b1n_f[idx - 82112] = ldin(b1n, idx - 82112, f); }
    else { int j = idx - 82240; b2n_f[j] = (j < 126) ? ldin(b2n, j, f) : 0.f; }
  }
}

// ---------------- init: f32 master states + bf16 mirror ----------------
__global__ void init_states_kernel(const void* in0, const int* __restrict__ flag,
                                   float* __restrict__ sf, u16* __restrict__ sbm)
{
  int f = *flag;
  const long total = (long)Bx * Nn * Dd;
  for (long i = (long)blockIdx.x * blockDim.x + threadIdx.x; i < total; i += (long)gridDim.x * blockDim.x){
    float v = ldin(in0, i, f);
    sf[i] = v; sbm[i] = f2b(v);
  }
}

// ---------------- CSR build ----------------
__global__ void count_kernel(const int* __restrict__ snk, int* __restrict__ cnt){
  int i = blockIdx.x * blockDim.x + threadIdx.x;
  if (i < Ee) atomicAdd(&cnt[snk[i]], 1);
}
__global__ void scan_kernel(const int* __restrict__ cnt, int* __restrict__ rowp){
  __shared__ int tot[1024];
  int t = threadIdx.x;
  int base = t * 10;
  int local[10]; int s = 0;
  #pragma unroll
  for (int i = 0; i < 10; i++){
    int v = (base + i < Nn) ? cnt[base + i] : 0;
    local[i] = s; s += v;
  }
  tot[t] = s;
  __syncthreads();
  for (int o = 1; o < 1024; o <<= 1){
    int v = (t >= o) ? tot[t - o] : 0;
    __syncthreads();
    tot[t] += v;
    __syncthreads();
  }
  int prefix = (t == 0) ? 0 : tot[t - 1];
  #pragma unroll
  for (int i = 0; i < 10; i++)
    if (base + i < Nn) rowp[base + i] = prefix + local[i];
  if (t == 1023) rowp[Nn] = tot[1023];
}
// CSR source list: slot p holds src of the edge at CSR position p (sink implied by row)
__global__ void fill_kernel(const int* __restrict__ src, const int* __restrict__ snk,
                            const int* __restrict__ rowp, int* __restrict__ cnt,
                            int* __restrict__ psrc){
  int i = blockIdx.x * blockDim.x + threadIdx.x;
  if (i < Ee){
    int s = snk[i];
    int p = rowp[s] + atomicAdd(&cnt[s], 1);
    psrc[p] = src[i];
  }
}

// ---------------- xform: per-node layer-1 halves, b1 FOLDED into Xa ----------------
// Xa[n] = states[n] @ W1[0:128] + b1 ; Xb[n] = states[n] @ W1[128:256]
__global__ __launch_bounds__(256) void xform_kernel(
  const u16* __restrict__ sbm, const u16* __restrict__ w1s,
  const float* __restrict__ b1f, u16* __restrict__ xab)
{
  __shared__ __align__(16) u16 w1h[16384];     // 32KB: one K-half of w1e, swizzled
  __shared__ __align__(16) u16 Yt[64 * 136];   // 17KB: store transpose (wave-private rows)
  int tid = threadIdx.x;
  int b = (blockIdx.x & 7) >> 1;
  int nt = ((blockIdx.x >> 3) << 1) + (blockIdx.x & 1);
  if (nt >= 157) return;                       // uniform per block; before any barrier
  int n0 = nt * 64;
  int w = tid >> 6, lane = tid & 63, m = lane & 15, quad = lane >> 4;
  int n = n0 + w * 16 + m;
  int nld = n < Nn ? n : Nn - 1;
  const u16* srow = sbm + (((size_t)b * Nn + nld) << 7);

  bf16x8 a[4];
  #pragma unroll
  for (int lk = 0; lk < 4; lk++) a[lk] = *(const bf16x8*)(srow + lk * 32 + quad * 8);

  const f32x4 z4 = {0.f, 0.f, 0.f, 0.f};
  int row_l = lane >> 2, seg = lane & 3;
  int nst = n0 + w * 16 + row_l;

  #pragma unroll
  for (int half = 0; half < 2; half++){
    __syncthreads();                           // prior w1h readers done
    {
      const uint4* g = (const uint4*)(w1s + half * 16384);
      uint4* l = (uint4*)w1h;
      #pragma unroll
      for (int i = 0; i < 8; i++) l[tid + i * 256] = g[tid + i * 256];
    }
    __syncthreads();
    f32x4 acc[8];
    #pragma unroll
    for (int ct = 0; ct < 8; ct++) acc[ct] = z4;
    #pragma unroll
    for (int lk = 0; lk < 4; lk++){
      #pragma unroll
      for (int ct = 0; ct < 8; ct++){
        bf16x8 bv = *(const bf16x8*)(w1h + (((lk * 4 + quad) << 7) + ct * 16 + m) * 8);
        acc[ct] = __builtin_amdgcn_mfma_f32_16x16x32_bf16(a[lk], bv, acc[ct], 0, 0, 0);
      }
    }
    #pragma unroll
    for (int ct = 0; ct < 8; ct++){
      float bb = (half == 0) ? b1f[ct * 16 + m] : 0.f;   // fold b1 into Xa
      #pragma unroll
      for (int i = 0; i < 4; i++)
        Yt[(w * 16 + quad * 4 + i) * 136 + ct * 16 + m] = f2b(acc[ct][i] + bb);
    }
    if (nst < Nn){
      const uint4* tp = (const uint4*)(Yt + (w * 16 + row_l) * 136 + seg * 32);
      uint4 x0 = tp[0], x1 = tp[1], x2 = tp[2], x3 = tp[3];
      uint4* gp = (uint4*)(xab + ((size_t)b * Nn + nst) * 256 + half * 128 + seg * 32);
      gp[0] = x0; gp[1] = x1; gp[2] = x2; gp[3] = x3;
    }
  }
}

// ---------------- gather v16: standalone, zero-LDS, grid-oversubscribed ----------------
// hs[n] = Σ_{e→n} relu(Xa[src]+Xb[n]). 16-node tiles x 16 thr/node (16B/thread/edge;
// wave = 4 nodes -> 4x256B contiguous rows per instruction). Sequential CSR walk
// per thread (v13/v14 lesson: chain tricks lose to locality — fix occupancy via
// GRID instead: 2504 blocks ~ 10/CU, no LDS, small VGPR -> TLP hides L2 latency).
__global__ __launch_bounds__(256) void gather_kernel(
  const u16* __restrict__ xab, const int* __restrict__ rowp, const int* __restrict__ psrc,
  u16* __restrict__ hs)
{
  int b = (blockIdx.x & 7) >> 1;
  int tile = ((blockIdx.x >> 3) << 1) + (blockIdx.x & 1);   // 0..624
  if (tile >= 625) return;
  int tid = threadIdx.x;
  int nl = tid >> 4, part = tid & 15;
  int n = tile * 16 + nl;                      // 625*16 == Nn exactly
  const u16* xb0 = xab + (size_t)b * Nn * 256;

  float xbf[8];
  {
    bf16x8 xv = *(const bf16x8*)(xb0 + (size_t)n * 256 + 128 + part * 8);
    #pragma unroll
    for (int j = 0; j < 8; j++) xbf[j] = (float)xv[j];
  }
  float acc[8];
  #pragma unroll
  for (int j = 0; j < 8; j++) acc[j] = 0.f;
  int r0 = rowp[n], r1 = rowp[n + 1];
  #pragma unroll 1
  for (int r = r0; r < r1; r++){
    int s = psrc[r];
    bf16x8 q = *(const bf16x8*)(xb0 + (size_t)s * 256 + part * 8);
    #pragma unroll
    for (int j = 0; j < 8; j++){
      float v = (float)q[j] + xbf[j];
      acc[j] += v > 0.f ? v : 0.f;
    }
  }
  union { u16 h[8]; uint4 v[2]; } hb;
  #pragma unroll
  for (int j = 0; j < 8; j++) hb.h[j] = f2b(acc[j]);
  uint4* hp = (uint4*)(hs + (((size_t)b * Nn + n) << 7) + part * 8);
  hp[0] = hb.v[0]; hp[1] = hb.v[1];
}

// ---------------- mlp v16: phase 2 (hs @ w2e) + phase 3 (node MLP) ----------------
// hs A-frags read directly from global (16B/lane coalesced). States staged via LDS
// (v12 pattern). NEVER runtime-index acc arrays (v7 lesson).
__global__ __launch_bounds__(256) void mlp_kernel(
  float* __restrict__ sf, u16* __restrict__ sbm, const u16* __restrict__ hs,
  const int* __restrict__ rowp,
  const u16* __restrict__ w2es, const float* __restrict__ b2ef,
  const u16* __restrict__ w1s, const u16* __restrict__ w2s,
  const float* __restrict__ b1f, const float* __restrict__ b2f2)
{
  __shared__ __align__(16) u16 ninp[64 * 200];
  __shared__ __align__(16) u16 Yt[64 * 136];
  int b = (blockIdx.x & 7) >> 1;
  int nt = ((blockIdx.x >> 3) << 1) + (blockIdx.x & 1);
  if (nt >= 157) return;
  int n0 = nt * 64;
  int tid = threadIdx.x;

  // stage states into ninp rows (wave-private rows; no barrier needed)
  {
    int nl = tid >> 2, part = tid & 3;
    int n = n0 + nl;
    uint4* dp = (uint4*)(ninp + nl * 200 + 64 + part * 32);
    if (n < Nn){
      const uint4* sp = (const uint4*)(sbm + (((size_t)b * Nn + n) << 7) + part * 32);
      #pragma unroll
      for (int i = 0; i < 4; i++) dp[i] = sp[i];
    } else {
      uint4 zz = {0, 0, 0, 0};
      #pragma unroll
      for (int i = 0; i < 4; i++) dp[i] = zz;
    }
  }

  int w = tid >> 6, lane = tid & 63, m = lane & 15, quad = lane >> 4;
  const f32x4 z4 = {0.f, 0.f, 0.f, 0.f};

  // ---- phase 2: incoming = hs @ w2e + deg*b2e -> ninp[0:64] ----
  {
    int nA = n0 + w * 16 + m;
    int nAld = nA < Nn ? nA : Nn - 1;
    const u16* hrow = hs + (((size_t)b * Nn + nAld) << 7);
    f32x4 acc[4];
    #pragma unroll
    for (int ct = 0; ct < 4; ct++) acc[ct] = z4;
    #pragma unroll
    for (int ks = 0; ks < 4; ks++){
      bf16x8 a = *(const bf16x8*)(hrow + ks * 32 + quad * 8);
      #pragma unroll
      for (int ct = 0; ct < 4; ct++){
        bf16x8 bv = *(const bf16x8*)(w2es + (((ks * 4 + quad) << 6) + ct * 16 + m) * 8);
        acc[ct] = __builtin_amdgcn_mfma_f32_16x16x32_bf16(a, bv, acc[ct], 0, 0, 0);
      }
    }
    #pragma unroll
    for (int i = 0; i < 4; i++){
      int n = n0 + w * 16 + quad * 4 + i;
      float deg = (n < Nn) ? (float)(rowp[n + 1] - rowp[n]) : 0.f;
      #pragma unroll
      for (int ct = 0; ct < 4; ct++)
        ninp[(w * 16 + quad * 4 + i) * 200 + ct * 16 + m] = f2b(acc[ct][i] + deg * b2ef[ct * 16 + m]);
    }
  }

  // ---- phase 3: node MLP ----
  f32x4 acc1[8];
  #pragma unroll
  for (int ct = 0; ct < 8; ct++) acc1[ct] = z4;
  #pragma unroll 1
  for (int ks = 0; ks < 6; ks++){
    bf16x8 a = *(const bf16x8*)(ninp + (w * 16 + m) * 200 + ks * 32 + quad * 8);
    #pragma unroll
    for (int ct = 0; ct < 8; ct++){
      bf16x8 bv = *(const bf16x8*)(w1s + (((ks * 4 + quad) << 7) + ct * 16 + m) * 8);
      acc1[ct] = __builtin_amdgcn_mfma_f32_16x16x32_bf16(a, bv, acc1[ct], 0, 0, 0);
    }
  }
  #pragma unroll
  for (int ct = 0; ct < 8; ct++){
    float bb = b1f[ct * 16 + m];
    #pragma unroll
    for (int i = 0; i < 4; i++){
      float v = acc1[ct][i] + bb;
      v = v > 0.f ? v : 0.f;
      Yt[(w * 16 + quad * 4 + i) * 136 + ct * 16 + m] = f2b(v);
    }
  }
  f32x4 acc2[8];
  #pragma unroll
  for (int ct = 0; ct < 8; ct++) acc2[ct] = z4;
  #pragma unroll 1
  for (int ko = 0; ko < 4; ko++){
    bf16x8 a2 = *(const bf16x8*)(Yt + (w * 16 + m) * 136 + ko * 32 + quad * 8);
    #pragma unroll
    for (int ct = 0; ct < 8; ct++){
      bf16x8 bv = *(const bf16x8*)(w2s + (((ko * 4 + quad) << 7) + ct * 16 + m) * 8);
      acc2[ct] = __builtin_amdgcn_mfma_f32_16x16x32_bf16(a2, bv, acc2[ct], 0, 0, 0);
    }
  }
  #pragma unroll
  for (int ct = 0; ct < 8; ct++){
    int u = ct * 16 + m;
    if (u < 126){
      float bb = b2f2[u];
      #pragma unroll
      for (int i = 0; i < 4; i++){
        int n = n0 + w * 16 + quad * 4 + i;
        if (n < Nn){
          size_t idx = (((size_t)b * Nn + n) << 7) + 2 + u;
          float v = sf[idx] + acc2[ct][i] + bb;
          sf[idx] = v;
          sbm[idx] = f2b(v);
        }
      }
    }
  }
}

// ---------------- extraction: states swizzle + direct-attn MFMA GEMM ----------------
__global__ void swz_s_kernel(const u16* __restrict__ sbm, u16* __restrict__ sswz)
{
  const long total = (long)Bx * KG * 128;
  for (long i = (long)blockIdx.x * blockDim.x + threadIdx.x; i < total; i += (long)gridDim.x * blockDim.x){
    int d = (int)(i & 127); long r = i >> 7;
    int kg = (int)(r % KG); int b = (int)(r / KG);
    union { u16 h[8]; uint4 v[2]; } t;
    if (kg < 1250){
      #pragma unroll
      for (int j = 0; j < 8; j++)
        t.h[j] = sbm[(((size_t)b * Nn + kg * 8 + j) << 7) + d];
    } else {
      #pragma unroll
      for (int j = 0; j < 8; j++) t.h[j] = 0;
    }
    *(uint4*)(sswz + i * 8) = t.v[0];
    *(uint4*)(sswz + i * 8 + 8) = t.v[1];
  }
}
// A-frags read DIRECTLY from attn (32B/lane contiguous; 4 quads = one 128B line)
__global__ __launch_bounds__(256) void extract2_kernel(
  const void* __restrict__ attn, const int* __restrict__ flag,
  const u16* __restrict__ sswz, float* __restrict__ part)
{
  int f = *flag;
  int blk = blockIdx.x;
  int kc = blk & 15, qt = (blk >> 4) & 3, b = blk >> 6;
  int tid = threadIdx.x, w = tid >> 6, lane = tid & 63, m = lane & 15, quad = lane >> 4;
  int qr = qt * 4 + w, q0 = qr * 16;
  int kg0 = kc * 80;
  int nsteps = (kc == 15) ? 13 : 20;
  long arow = ((long)(b * Qq + q0 + m)) * Nn;
  const u16* ab16 = (const u16*)attn + arow;
  const float* af32 = (const float*)attn + arow;
  const u16* sbase = sswz + ((size_t)b) * KG * 1024;
  f32x4 acc[8];
  const f32x4 z4 = {0.f, 0.f, 0.f, 0.f};
  #pragma unroll
  for (int ct = 0; ct < 8; ct++) acc[ct] = z4;
  #pragma unroll 1
  for (int t = 0; t < nsteps; t++){
    int kg = kg0 + t * 4 + quad;
    bf16x8 a;
    if (kg < 1250){
      if (f){
        a = *(const bf16x8*)(ab16 + kg * 8);
      } else {
        const float* ap = af32 + kg * 8;
        float4 p0 = *(const float4*)ap;
        float4 p1 = *(const float4*)(ap + 4);
        a[0] = (__bf16)p0.x; a[1] = (__bf16)p0.y; a[2] = (__bf16)p0.z; a[3] = (__bf16)p0.w;
        a[4] = (__bf16)p1.x; a[5] = (__bf16)p1.y; a[6] = (__bf16)p1.z; a[7] = (__bf16)p1.w;
      }
    } else {
      #pragma unroll
      for (int j = 0; j < 8; j++) a[j] = (__bf16)0.f;
    }
    #pragma unroll
    for (int ct = 0; ct < 8; ct++){
      bf16x8 bv = *(const bf16x8*)(sbase + ((size_t)kg * 128 + ct * 16 + m) * 8);
      acc[ct] = __builtin_amdgcn_mfma_f32_16x16x32_bf16(a, bv, acc[ct], 0, 0, 0);
    }
  }
  #pragma unroll
  for (int ct = 0; ct < 8; ct++){
    #pragma unroll
    for (int i = 0; i < 4; i++)
      part[(((size_t)(kc * 4 + b)) * Qq + q0 + quad * 4 + i) * 128 + ct * 16 + m] = acc[ct][i];
  }
}

// ---------------- finalize: out = [poses | sum(16 partials)] ----------------
__global__ void final_kernel(const void* __restrict__ poses, const int* __restrict__ flag,
                             const float* __restrict__ part, void* __restrict__ out)
{
  int f = *flag;
  const long total = (long)Bx * Qq * (Pp + Dd);
  for (long idx = (long)blockIdx.x * blockDim.x + threadIdx.x; idx < total; idx += (long)gridDim.x * blockDim.x){
    int j = (int)(idx % (Pp + Dd));
    long bq = idx / (Pp + Dd);
    float v;
    if (j < Pp){
      v = ldin(poses, bq * Pp + j, f);
    } else {
      int dd = j - Pp;
      int b = (int)(bq >> 8), q = (int)(bq & 255);
      v = 0.f;
      #pragma unroll
      for (int kc = 0; kc < 16; kc++)
        v += part[(((size_t)(kc * 4 + b) * Qq + q) << 7) + dd];
    }
    if (f) ((u16*)out)[idx] = f2b(v);
    else ((float*)out)[idx] = v;
  }
}

extern "C" void kernel_launch(void* const* d_in, const int* in_sizes, int n_in,
                              void* d_out, int out_size, void* d_ws, size_t ws_size,
                              hipStream_t stream)
{
  const void* in_states = d_in[0];
  const void* in_poses  = d_in[1];
  const void* in_attn   = d_in[2];
  const int*  in_src    = (const int*)d_in[3];
  const int*  in_snk    = (const int*)d_in[4];
  const void* in_w1e = d_in[5];  const void* in_b1e = d_in[6];
  const void* in_w2e = d_in[7];  const void* in_b2e = d_in[8];
  const void* in_w1n = d_in[9];  const void* in_b1n = d_in[10];
  const void* in_w2n = d_in[11]; const void* in_b2n = d_in[12];

  char* ws = (char*)d_ws;
  size_t off = 0;
  auto alloc = [&](size_t bytes){ size_t o = off; off = (off + bytes + 255) & ~(size_t)255; return o; };
  size_t o_sf   = alloc((size_t)Bx * Nn * Dd * 4);
  size_t o_sb   = alloc((size_t)Bx * Nn * Dd * 2);
  size_t o_xab  = alloc((size_t)Bx * Nn * 256 * 2);   // 20.5 MB: [b][n][Xa+b1|Xb]
  size_t o_hs   = alloc((size_t)Bx * Nn * 128 * 2);   // 10.2 MB: hidden sums
  size_t o_rowp = alloc((size_t)(Nn + 1) * 4);
  size_t o_rcnt = alloc((size_t)Nn * 4);
  size_t o_psrc = alloc((size_t)Ee * 4);
  size_t o_w1e  = alloc(32768 * 2);
  size_t o_w2e  = alloc(8192 * 2);
  size_t o_w1n  = alloc(24576 * 2);
  size_t o_w2n  = alloc(16384 * 2);
  size_t o_b1e  = alloc(128 * 4);
  size_t o_b2e  = alloc(64 * 4);
  size_t o_b1n  = alloc(128 * 4);
  size_t o_b2n  = alloc(128 * 4);
  size_t o_flag = alloc(4);

  size_t sswzB = (size_t)Bx * KG * 128 * 8 * 2;    // 10.3 MB
  size_t partB = (size_t)16 * Bx * Qq * Dd * 4;    // 8.4 MB
  size_t o_sswz = alloc(sswzB);
  size_t o_part = alloc(partB);

  float* sf    = (float*)(ws + o_sf);
  u16*   sbm   = (u16*)(ws + o_sb);
  u16*   xab   = (u16*)(ws + o_xab);
  u16*   hs    = (u16*)(ws + o_hs);
  int*   rowp  = (int*)(ws + o_rowp);
  int*   rcnt  = (int*)(ws + o_rcnt);
  int*   psrc  = (int*)(ws + o_psrc);
  u16*   w1e_s = (u16*)(ws + o_w1e);
  u16*   w2e_s = (u16*)(ws + o_w2e);
  u16*   w1n_s = (u16*)(ws + o_w1n);
  u16*   w2n_s = (u16*)(ws + o_w2n);
  float* b1e_f = (float*)(ws + o_b1e);
  float* b2e_f = (float*)(ws + o_b2e);
  float* b1n_f = (float*)(ws + o_b1n);
  float* b2n_f = (float*)(ws + o_b2n);
  int*   flag  = (int*)(ws + o_flag);
  u16*   sswz  = (u16*)(ws + o_sswz);
  float* part  = (float*)(ws + o_part);

  probe_kernel<<<1, 64, 0, stream>>>(in_states, flag);
  prep_kernel<<<322, 256, 0, stream>>>(in_w1e, in_b1e, in_w2e, in_b2e,
                                       in_w1n, in_b1n, in_w2n, in_b2n, flag,
                                       w1e_s, w2e_s, w1n_s, w2n_s,
                                       b1e_f, b2e_f, b1n_f, b2n_f);
  init_states_kernel<<<1024, 256, 0, stream>>>(in_states, flag, sf, sbm);

  hipMemsetAsync(rcnt, 0, (size_t)Nn * 4, stream);
  count_kernel<<<(Ee + 255) / 256, 256, 0, stream>>>(in_snk, rcnt);
  scan_kernel<<<1, 1024, 0, stream>>>(rcnt, rowp);
  hipMemsetAsync(rcnt, 0, (size_t)Nn * 4, stream);
  fill_kernel<<<(Ee + 255) / 256, 256, 0, stream>>>(in_src, in_snk, rowp, rcnt, psrc);

  for (int step = 0; step < 3; step++){
    xform_kernel<<<632, 256, 0, stream>>>(sbm, w1e_s, b1e_f, xab);
    gather_kernel<<<2504, 256, 0, stream>>>(xab, rowp, psrc, hs);
    mlp_kernel<<<632, 256, 0, stream>>>(sf, sbm, hs, rowp,
                                        w2e_s, b2e_f,
                                        w1n_s, w2n_s, b1n_f, b2n_f);
  }
  swz_s_kernel<<<2504, 256, 0, stream>>>(sbm, sswz);
  extract2_kernel<<<256, 256, 0, stream>>>(in_attn, flag, sswz, part);
  final_kernel<<<540, 256, 0, stream>>>(in_poses, flag, part, d_out);
}

// Round 17
// 375.255 us; speedup vs baseline: 1.0632x; 1.0632x over previous
//
#include <hip/hip_runtime.h>

// Problem constants (from reference)
#define Bx 4
#define Nn 10000
#define Ee 160000
#define Qq 256
#define Dd 128
#define Mm 64
#define Uu 126
#define Hh 128
#define Pp 7

// N padded to groups of 8 (1250 groups) + 2 pad groups for ragged K-tail
#define KG 1252

typedef unsigned short u16;
typedef __bf16 bf16x8 __attribute__((ext_vector_type(8)));
typedef float f32x4 __attribute__((ext_vector_type(4)));

__device__ __forceinline__ float b2f(u16 h){
  unsigned u = ((unsigned)h) << 16; float f; __builtin_memcpy(&f, &u, 4); return f;
}
// hardware RNE f32->bf16
__device__ __forceinline__ u16 f2b(float f){
  __bf16 h = (__bf16)f; u16 r; __builtin_memcpy(&r, &h, 2); return r;
}
__device__ __forceinline__ float ldin(const void* p, long i, int flag){
  return flag ? b2f(((const u16*)p)[i]) : ((const float*)p)[i];
}

// ---------------- dtype probe ----------------
__global__ void probe_kernel(const void* in0, int* flag){
  if (threadIdx.x == 0 && blockIdx.x == 0){
    const u16* p = (const u16*)in0;
    int cnt = 0;
    for (int i = 0; i < 256; i++){
      float a = fabsf(b2f(p[i]));
      if (a > 0.0009765625f && a < 32.0f) cnt++;
    }
    *flag = (cnt >= 240) ? 1 : 0;
  }
}

// ---------------- weight prep: convert + swizzle to MFMA B-frag layout ----------------
__global__ void prep_kernel(const void* w1e, const void* b1e, const void* w2e, const void* b2e,
                            const void* w1n, const void* b1n, const void* w2n, const void* b2n,
                            const int* __restrict__ flag,
                            u16* w1e_s, u16* w2e_s, u16* w1n_s, u16* w2n_s,
                            float* b1e_f, float* b2e_f, float* b1n_f, float* b2n_f)
{
  int f = *flag;
  for (int idx = blockIdx.x * blockDim.x + threadIdx.x; idx < 82368; idx += gridDim.x * blockDim.x){
    if (idx < 32768){                                   // w1e (256,128)
      int k = idx >> 7, h = idx & 127;
      w1e_s[(k >> 3) * 1024 + h * 8 + (k & 7)] = f2b(ldin(w1e, idx, f));
    } else if (idx < 40960){                            // w2e (128,64)
      int i2 = idx - 32768; int k = i2 >> 6, m2 = i2 & 63;
      w2e_s[(k >> 3) * 512 + m2 * 8 + (k & 7)] = f2b(ldin(w2e, i2, f));
    } else if (idx < 65536){                            // w1n (192,128)
      int i2 = idx - 40960; int k = i2 >> 7, h = i2 & 127;
      w1n_s[(k >> 3) * 1024 + h * 8 + (k & 7)] = f2b(ldin(w1n, i2, f));
    } else if (idx < 81920){                            // w2n (128,126) padded to 128 cols
      int i2 = idx - 65536; int k = i2 >> 7, u = i2 & 127;
      float v = (u < 126) ? ldin(w2n, (long)k * 126 + u, f) : 0.f;
      w2n_s[(k >> 3) * 1024 + u * 8 + (k & 7)] = f2b(v);
    } else if (idx < 82048){ b1e_f[idx - 81920] = ldin(b1e, idx - 81920, f); }
    else if (idx < 82112){ b2e_f[idx - 82048] = ldin(b2e, idx - 82048, f); }
    else if (idx < 82240){ b1n_f[idx - 82112] = ldin(b1n, idx - 82112, f); }
    else { int j = idx - 82240; b2n_f[j] = (j < 126) ? ldin(b2n, j, f) : 0.f; }
  }
}

// ---------------- init: f32 master states + bf16 mirror; fused sink-degree count ----------------
__global__ void init_states_kernel(const void* in0, const int* __restrict__ flag,
                                   const int* __restrict__ snk,
                                   float* __restrict__ sf, u16* __restrict__ sbm,
                                   int* __restrict__ cnt)
{
  int f = *flag;
  const long total = (long)Bx * Nn * Dd;
  long base = (long)blockIdx.x * blockDim.x + threadIdx.x;
  for (long i = base; i < total; i += (long)gridDim.x * blockDim.x){
    float v = ldin(in0, i, f);
    sf[i] = v; sbm[i] = f2b(v);
  }
  for (long i = base; i < Ee; i += (long)gridDim.x * blockDim.x)
    atomicAdd(&cnt[snk[(int)i]], 1);
}

// ---------------- CSR build ----------------
__global__ void scan_kernel(const int* __restrict__ cnt, int* __restrict__ rowp){
  __shared__ int tot[1024];
  int t = threadIdx.x;
  int base = t * 10;
  int local[10]; int s = 0;
  #pragma unroll
  for (int i = 0; i < 10; i++){
    int v = (base + i < Nn) ? cnt[base + i] : 0;
    local[i] = s; s += v;
  }
  tot[t] = s;
  __syncthreads();
  for (int o = 1; o < 1024; o <<= 1){
    int v = (t >= o) ? tot[t - o] : 0;
    __syncthreads();
    tot[t] += v;
    __syncthreads();
  }
  int prefix = (t == 0) ? 0 : tot[t - 1];
  #pragma unroll
  for (int i = 0; i < 10; i++)
    if (base + i < Nn) rowp[base + i] = prefix + local[i];
  if (t == 1023) rowp[Nn] = tot[1023];
}
// CSR source list: slot p holds src of the edge at CSR position p (sink implied by row)
__global__ void fill_kernel(const int* __restrict__ src, const int* __restrict__ snk,
                            const int* __restrict__ rowp, int* __restrict__ cnt,
                            int* __restrict__ psrc){
  int i = blockIdx.x * blockDim.x + threadIdx.x;
  if (i < Ee){
    int s = snk[i];
    int p = rowp[s] + atomicAdd(&cnt[s], 1);
    psrc[p] = src[i];
  }
}

// ---------------- xform: per-node layer-1 halves, b1 FOLDED into Xa ----------------
// Xa[n] = states[n] @ W1[0:128] + b1 ; Xb[n] = states[n] @ W1[128:256]
__global__ __launch_bounds__(256) void xform_kernel(
  const u16* __restrict__ sbm, const u16* __restrict__ w1s,
  const float* __restrict__ b1f, u16* __restrict__ xab)
{
  __shared__ __align__(16) u16 w1h[16384];     // 32KB: one K-half of w1e, swizzled
  __shared__ __align__(16) u16 Yt[64 * 136];   // 17KB: store transpose (wave-private rows)
  int tid = threadIdx.x;
  int b = (blockIdx.x & 7) >> 1;
  int nt = ((blockIdx.x >> 3) << 1) + (blockIdx.x & 1);
  if (nt >= 157) return;                       // uniform per block; before any barrier
  int n0 = nt * 64;
  int w = tid >> 6, lane = tid & 63, m = lane & 15, quad = lane >> 4;
  int n = n0 + w * 16 + m;
  int nld = n < Nn ? n : Nn - 1;
  const u16* srow = sbm + (((size_t)b * Nn + nld) << 7);

  bf16x8 a[4];
  #pragma unroll
  for (int lk = 0; lk < 4; lk++) a[lk] = *(const bf16x8*)(srow + lk * 32 + quad * 8);

  const f32x4 z4 = {0.f, 0.f, 0.f, 0.f};
  int row_l = lane >> 2, seg = lane & 3;
  int nst = n0 + w * 16 + row_l;

  #pragma unroll
  for (int half = 0; half < 2; half++){
    __syncthreads();                           // prior w1h readers done
    {
      const uint4* g = (const uint4*)(w1s + half * 16384);
      uint4* l = (uint4*)w1h;
      #pragma unroll
      for (int i = 0; i < 8; i++) l[tid + i * 256] = g[tid + i * 256];
    }
    __syncthreads();
    f32x4 acc[8];
    #pragma unroll
    for (int ct = 0; ct < 8; ct++) acc[ct] = z4;
    #pragma unroll
    for (int lk = 0; lk < 4; lk++){
      #pragma unroll
      for (int ct = 0; ct < 8; ct++){
        bf16x8 bv = *(const bf16x8*)(w1h + (((lk * 4 + quad) << 7) + ct * 16 + m) * 8);
        acc[ct] = __builtin_amdgcn_mfma_f32_16x16x32_bf16(a[lk], bv, acc[ct], 0, 0, 0);
      }
    }
    #pragma unroll
    for (int ct = 0; ct < 8; ct++){
      float bb = (half == 0) ? b1f[ct * 16 + m] : 0.f;   // fold b1 into Xa
      #pragma unroll
      for (int i = 0; i < 4; i++)
        Yt[(w * 16 + quad * 4 + i) * 136 + ct * 16 + m] = f2b(acc[ct][i] + bb);
    }
    if (nst < Nn){
      const uint4* tp = (const uint4*)(Yt + (w * 16 + row_l) * 136 + seg * 32);
      uint4 x0 = tp[0], x1 = tp[1], x2 = tp[2], x3 = tp[3];
      uint4* gp = (uint4*)(xab + ((size_t)b * Nn + nst) * 256 + half * 128 + seg * 32);
      gp[0] = x0; gp[1] = x1; gp[2] = x2; gp[3] = x3;
    }
  }
}

// ---------------- node v12/v15: fused edge+node, sequential gather ----------------
// incoming[n] = (Σ_{e→n} relu(Xa[src]+Xb[n])) @ W2e + deg(n)*b2e (linearity fusion).
// Sequential 4-thr/node CSR walk is a LOCAL OPTIMUM: v13 (reg prefetch + unroll),
// v14 (chain split), v16 (standalone oversubscribed gather) all regressed or were
// neutral — locality + fused phases beat chain/occupancy tricks here.
// NEVER runtime-index acc arrays (v7 lesson: scratch blowup).
__global__ __launch_bounds__(256) void node_kernel(
  float* __restrict__ sf, u16* __restrict__ sbm, const u16* __restrict__ xab,
  const int* __restrict__ rowp, const int* __restrict__ psrc,
  const u16* __restrict__ w2es, const float* __restrict__ b2ef,
  const u16* __restrict__ w1s, const u16* __restrict__ w2s,
  const float* __restrict__ b1f, const float* __restrict__ b2f2)
{
  __shared__ __align__(16) u16 ninp[64 * 200];
  __shared__ __align__(16) u16 hsYt[64 * 136];   // phase2 A-operand, then phase3 Yt
  int b = (blockIdx.x & 7) >> 1;
  int nt = ((blockIdx.x >> 3) << 1) + (blockIdx.x & 1);
  if (nt >= 157) return;
  int n0 = nt * 64;
  int tid = threadIdx.x;

  // ---- phase 1: hsum[n] = Σ relu(Xa[src]+Xb[n]) over in-edges; states -> ninp ----
  {
    int nl = tid >> 2, part = tid & 3;
    int n = n0 + nl;
    float acc[32];
    #pragma unroll
    for (int i = 0; i < 32; i++) acc[i] = 0.f;
    if (n < Nn){
      float xbf[32];
      {
        const uint4* xp = (const uint4*)(xab + ((size_t)b * Nn + n) * 256 + 128 + part * 32);
        union { uint4 v; u16 h[8]; } q[4];
        q[0].v = xp[0]; q[1].v = xp[1]; q[2].v = xp[2]; q[3].v = xp[3];
        #pragma unroll
        for (int t4 = 0; t4 < 4; t4++)
          #pragma unroll
          for (int j = 0; j < 8; j++) xbf[t4 * 8 + j] = b2f(q[t4].h[j]);
      }
      int r0 = rowp[n], r1 = rowp[n + 1];
      const u16* xb0 = xab + (size_t)b * Nn * 256;
      for (int r = r0; r < r1; r++){
        int s = psrc[r];
        const uint4* xp = (const uint4*)(xb0 + (size_t)s * 256 + part * 32);
        union { uint4 v; u16 h[8]; } q[4];
        q[0].v = xp[0]; q[1].v = xp[1]; q[2].v = xp[2]; q[3].v = xp[3];
        #pragma unroll
        for (int t4 = 0; t4 < 4; t4++)
          #pragma unroll
          for (int j = 0; j < 8; j++){
            float v = b2f(q[t4].h[j]) + xbf[t4 * 8 + j];
            acc[t4 * 8 + j] += v > 0.f ? v : 0.f;
          }
      }
    }
    // write hs row (bf16) — consumed by this wave's phase-2 MFMA
    union { u16 h[32]; uint4 v[4]; } hb;
    #pragma unroll
    for (int i = 0; i < 32; i++) hb.h[i] = f2b(acc[i]);
    uint4* hp = (uint4*)(hsYt + nl * 136 + part * 32);
    hp[0] = hb.v[0]; hp[1] = hb.v[1]; hp[2] = hb.v[2]; hp[3] = hb.v[3];
    // states part of ninp
    uint4* dp = (uint4*)(ninp + nl * 200 + 64 + part * 32);
    if (n < Nn){
      const uint4* sp = (const uint4*)(sbm + (((size_t)b * Nn + n) << 7) + part * 32);
      #pragma unroll
      for (int i = 0; i < 4; i++) dp[i] = sp[i];
    } else {
      uint4 zz = {0, 0, 0, 0};
      #pragma unroll
      for (int i = 0; i < 4; i++) dp[i] = zz;
    }
  }
  // no barrier: wave w wrote hs/ninp rows [16w,16w+16) and reads only those below

  int w = tid >> 6, lane = tid & 63, m = lane & 15, quad = lane >> 4;
  const f32x4 z4 = {0.f, 0.f, 0.f, 0.f};

  // ---- phase 2: incoming = hs @ w2e + deg*b2e -> ninp[0:64] ----
  {
    f32x4 acc[4];
    #pragma unroll
    for (int ct = 0; ct < 4; ct++) acc[ct] = z4;
    #pragma unroll
    for (int ks = 0; ks < 4; ks++){
      bf16x8 a = *(const bf16x8*)(hsYt + (w * 16 + m) * 136 + ks * 32 + quad * 8);
      #pragma unroll
      for (int ct = 0; ct < 4; ct++){
        bf16x8 bv = *(const bf16x8*)(w2es + (((ks * 4 + quad) << 6) + ct * 16 + m) * 8);
        acc[ct] = __builtin_amdgcn_mfma_f32_16x16x32_bf16(a, bv, acc[ct], 0, 0, 0);
      }
    }
    #pragma unroll
    for (int i = 0; i < 4; i++){
      int n = n0 + w * 16 + quad * 4 + i;
      float deg = (n < Nn) ? (float)(rowp[n + 1] - rowp[n]) : 0.f;
      #pragma unroll
      for (int ct = 0; ct < 4; ct++)
        ninp[(w * 16 + quad * 4 + i) * 200 + ct * 16 + m] = f2b(acc[ct][i] + deg * b2ef[ct * 16 + m]);
    }
  }

  // ---- phase 3: node MLP ----
  f32x4 acc1[8];
  #pragma unroll
  for (int ct = 0; ct < 8; ct++) acc1[ct] = z4;
  #pragma unroll 1
  for (int ks = 0; ks < 6; ks++){
    bf16x8 a = *(const bf16x8*)(ninp + (w * 16 + m) * 200 + ks * 32 + quad * 8);
    #pragma unroll
    for (int ct = 0; ct < 8; ct++){
      bf16x8 bv = *(const bf16x8*)(w1s + (((ks * 4 + quad) << 7) + ct * 16 + m) * 8);
      acc1[ct] = __builtin_amdgcn_mfma_f32_16x16x32_bf16(a, bv, acc1[ct], 0, 0, 0);
    }
  }
  #pragma unroll
  for (int ct = 0; ct < 8; ct++){
    float bb = b1f[ct * 16 + m];
    #pragma unroll
    for (int i = 0; i < 4; i++){
      float v = acc1[ct][i] + bb;
      v = v > 0.f ? v : 0.f;
      hsYt[(w * 16 + quad * 4 + i) * 136 + ct * 16 + m] = f2b(v);
    }
  }
  f32x4 acc2[8];
  #pragma unroll
  for (int ct = 0; ct < 8; ct++) acc2[ct] = z4;
  #pragma unroll 1
  for (int ko = 0; ko < 4; ko++){
    bf16x8 a2 = *(const bf16x8*)(hsYt + (w * 16 + m) * 136 + ko * 32 + quad * 8);
    #pragma unroll
    for (int ct = 0; ct < 8; ct++){
      bf16x8 bv = *(const bf16x8*)(w2s + (((ko * 4 + quad) << 7) + ct * 16 + m) * 8);
      acc2[ct] = __builtin_amdgcn_mfma_f32_16x16x32_bf16(a2, bv, acc2[ct], 0, 0, 0);
    }
  }
  #pragma unroll
  for (int ct = 0; ct < 8; ct++){
    int u = ct * 16 + m;
    if (u < 126){
      float bb = b2f2[u];
      #pragma unroll
      for (int i = 0; i < 4; i++){
        int n = n0 + w * 16 + quad * 4 + i;
        if (n < Nn){
          size_t idx = (((size_t)b * Nn + n) << 7) + 2 + u;
          float v = sf[idx] + acc2[ct][i] + bb;
          sf[idx] = v;
          sbm[idx] = f2b(v);
        }
      }
    }
  }
}

// ---------------- extraction: states swizzle + direct-attn MFMA GEMM ----------------
__global__ void swz_s_kernel(const u16* __restrict__ sbm, u16* __restrict__ sswz)
{
  const long total = (long)Bx * KG * 128;
  for (long i = (long)blockIdx.x * blockDim.x + threadIdx.x; i < total; i += (long)gridDim.x * blockDim.x){
    int d = (int)(i & 127); long r = i >> 7;
    int kg = (int)(r % KG); int b = (int)(r / KG);
    union { u16 h[8]; uint4 v[2]; } t;
    if (kg < 1250){
      #pragma unroll
      for (int j = 0; j < 8; j++)
        t.h[j] = sbm[(((size_t)b * Nn + kg * 8 + j) << 7) + d];
    } else {
      #pragma unroll
      for (int j = 0; j < 8; j++) t.h[j] = 0;
    }
    *(uint4*)(sswz + i * 8) = t.v[0];
    *(uint4*)(sswz + i * 8 + 8) = t.v[1];
  }
}
// 32 K-chunks (512 blocks = 2/CU; 16 chunks was 1 block/CU -> grid-starved).
// A-frags read DIRECTLY from attn (32B/lane contiguous; 4 quads = one 128B line).
__global__ __launch_bounds__(256) void extract2_kernel(
  const void* __restrict__ attn, const int* __restrict__ flag,
  const u16* __restrict__ sswz, float* __restrict__ part)
{
  int f = *flag;
  int blk = blockIdx.x;
  int kc = blk & 31, qt = (blk >> 5) & 3, b = blk >> 7;
  int tid = threadIdx.x, w = tid >> 6, lane = tid & 63, m = lane & 15, quad = lane >> 4;
  int qr = qt * 4 + w, q0 = qr * 16;
  int kg0 = kc * 40;
  int nsteps = (kc == 31) ? 3 : 10;            // tail: 1240..1251 covered by 3 steps
  long arow = ((long)(b * Qq + q0 + m)) * Nn;
  const u16* ab16 = (const u16*)attn + arow;
  const float* af32 = (const float*)attn + arow;
  const u16* sbase = sswz + ((size_t)b) * KG * 1024;
  f32x4 acc[8];
  const f32x4 z4 = {0.f, 0.f, 0.f, 0.f};
  #pragma unroll
  for (int ct = 0; ct < 8; ct++) acc[ct] = z4;
  #pragma unroll 1
  for (int t = 0; t < nsteps; t++){
    int kg = kg0 + t * 4 + quad;
    int kgc = kg < KG ? kg : 0;                // clamp B-frag addr; a=0 keeps math exact
    bf16x8 a;
    if (kg < 1250){
      if (f){
        a = *(const bf16x8*)(ab16 + kg * 8);
      } else {
        const float* ap = af32 + kg * 8;
        float4 p0 = *(const float4*)ap;
        float4 p1 = *(const float4*)(ap + 4);
        a[0] = (__bf16)p0.x; a[1] = (__bf16)p0.y; a[2] = (__bf16)p0.z; a[3] = (__bf16)p0.w;
        a[4] = (__bf16)p1.x; a[5] = (__bf16)p1.y; a[6] = (__bf16)p1.z; a[7] = (__bf16)p1.w;
      }
    } else {
      #pragma unroll
      for (int j = 0; j < 8; j++) a[j] = (__bf16)0.f;
    }
    #pragma unroll
    for (int ct = 0; ct < 8; ct++){
      bf16x8 bv = *(const bf16x8*)(sbase + ((size_t)kgc * 128 + ct * 16 + m) * 8);
      acc[ct] = __builtin_amdgcn_mfma_f32_16x16x32_bf16(a, bv, acc[ct], 0, 0, 0);
    }
  }
  #pragma unroll
  for (int ct = 0; ct < 8; ct++){
    #pragma unroll
    for (int i = 0; i < 4; i++)
      part[(((size_t)(kc * 4 + b)) * Qq + q0 + quad * 4 + i) * 128 + ct * 16 + m] = acc[ct][i];
  }
}

// ---------------- finalize: out = [poses | sum(32 partials)] ----------------
__global__ void final_kernel(const void* __restrict__ poses, const int* __restrict__ flag,
                             const float* __restrict__ part, void* __restrict__ out)
{
  int f = *flag;
  const long total = (long)Bx * Qq * (Pp + Dd);
  for (long idx = (long)blockIdx.x * blockDim.x + threadIdx.x; idx < total; idx += (long)gridDim.x * blockDim.x){
    int j = (int)(idx % (Pp + Dd));
    long bq = idx / (Pp + Dd);
    float v;
    if (j < Pp){
      v = ldin(poses, bq * Pp + j, f);
    } else {
      int dd = j - Pp;
      int b = (int)(bq >> 8), q = (int)(bq & 255);
      v = 0.f;
      #pragma unroll
      for (int kc = 0; kc < 32; kc++)
        v += part[(((size_t)(kc * 4 + b) * Qq + q) << 7) + dd];
    }
    if (f) ((u16*)out)[idx] = f2b(v);
    else ((float*)out)[idx] = v;
  }
}

extern "C" void kernel_launch(void* const* d_in, const int* in_sizes, int n_in,
                              void* d_out, int out_size, void* d_ws, size_t ws_size,
                              hipStream_t stream)
{
  const void* in_states = d_in[0];
  const void* in_poses  = d_in[1];
  const void* in_attn   = d_in[2];
  const int*  in_src    = (const int*)d_in[3];
  const int*  in_snk    = (const int*)d_in[4];
  const void* in_w1e = d_in[5];  const void* in_b1e = d_in[6];
  const void* in_w2e = d_in[7];  const void* in_b2e = d_in[8];
  const void* in_w1n = d_in[9];  const void* in_b1n = d_in[10];
  const void* in_w2n = d_in[11]; const void* in_b2n = d_in[12];

  char* ws = (char*)d_ws;
  size_t off = 0;
  auto alloc = [&](size_t bytes){ size_t o = off; off = (off + bytes + 255) & ~(size_t)255; return o; };
  size_t o_sf   = alloc((size_t)Bx * Nn * Dd * 4);
  size_t o_sb   = alloc((size_t)Bx * Nn * Dd * 2);
  size_t o_xab  = alloc((size_t)Bx * Nn * 256 * 2);   // 20.5 MB: [b][n][Xa+b1|Xb]
  size_t o_rowp = alloc((size_t)(Nn + 1) * 4);
  size_t o_rcnt = alloc((size_t)Nn * 4);
  size_t o_psrc = alloc((size_t)Ee * 4);
  size_t o_w1e  = alloc(32768 * 2);
  size_t o_w2e  = alloc(8192 * 2);
  size_t o_w1n  = alloc(24576 * 2);
  size_t o_w2n  = alloc(16384 * 2);
  size_t o_b1e  = alloc(128 * 4);
  size_t o_b2e  = alloc(64 * 4);
  size_t o_b1n  = alloc(128 * 4);
  size_t o_b2n  = alloc(128 * 4);
  size_t o_flag = alloc(4);

  size_t sswzB = (size_t)Bx * KG * 128 * 8 * 2;    // 10.3 MB
  size_t partB = (size_t)32 * Bx * Qq * Dd * 4;    // 16.8 MB
  size_t o_sswz = alloc(sswzB);
  size_t o_part = alloc(partB);

  float* sf    = (float*)(ws + o_sf);
  u16*   sbm   = (u16*)(ws + o_sb);
  u16*   xab   = (u16*)(ws + o_xab);
  int*   rowp  = (int*)(ws + o_rowp);
  int*   rcnt  = (int*)(ws + o_rcnt);
  int*   psrc  = (int*)(ws + o_psrc);
  u16*   w1e_s = (u16*)(ws + o_w1e);
  u16*   w2e_s = (u16*)(ws + o_w2e);
  u16*   w1n_s = (u16*)(ws + o_w1n);
  u16*   w2n_s = (u16*)(ws + o_w2n);
  float* b1e_f = (float*)(ws + o_b1e);
  float* b2e_f = (float*)(ws + o_b2e);
  float* b1n_f = (float*)(ws + o_b1n);
  float* b2n_f = (float*)(ws + o_b2n);
  int*   flag  = (int*)(ws + o_flag);
  u16*   sswz  = (u16*)(ws + o_sswz);
  float* part  = (float*)(ws + o_part);

  hipMemsetAsync(rcnt, 0, (size_t)Nn * 4, stream);
  probe_kernel<<<1, 64, 0, stream>>>(in_states, flag);
  prep_kernel<<<322, 256, 0, stream>>>(in_w1e, in_b1e, in_w2e, in_b2e,
                                       in_w1n, in_b1n, in_w2n, in_b2n, flag,
                                       w1e_s, w2e_s, w1n_s, w2n_s,
                                       b1e_f, b2e_f, b1n_f, b2n_f);
  init_states_kernel<<<1024, 256, 0, stream>>>(in_states, flag, in_snk, sf, sbm, rcnt);

  scan_kernel<<<1, 1024, 0, stream>>>(rcnt, rowp);
  hipMemsetAsync(rcnt, 0, (size_t)Nn * 4, stream);
  fill_kernel<<<(Ee + 255) / 256, 256, 0, stream>>>(in_src, in_snk, rowp, rcnt, psrc);

  for (int step = 0; step < 3; step++){
    xform_kernel<<<632, 256, 0, stream>>>(sbm, w1e_s, b1e_f, xab);
    node_kernel<<<632, 256, 0, stream>>>(sf, sbm, xab, rowp, psrc,
                                         w2e_s, b2e_f,
                                         w1n_s, w2n_s, b1n_f, b2n_f);
  }
  swz_s_kernel<<<2504, 256, 0, stream>>>(sbm, sswz);
  extract2_kernel<<<512, 256, 0, stream>>>(in_attn, flag, sswz, part);
  final_kernel<<<540, 256, 0, stream>>>(in_poses, flag, part, d_out);
}